// Round 5
// baseline (451.731 us; speedup 1.0000x reference)
//
#include <hip/hip_runtime.h>

// GraphAttentionLayer: B=8, N=2048, F=256, H=8, D=32. f32 inputs, f32 outputs
// (out0 [8,2048,256], out1 = attn.mean over heads [8,2048,2048]). adj int32.
// Pipeline: pack adj->bits | transpose W->bf16 | QKV gemm (MFMA) | pass1 (row
// sum of exp(s-20), fixed shift -- exact in f32 since |s*SCALE| < 3) | pass2
// (probs -> attn-mean + PV) | oproj + LN. Internal tensors bf16 in ws.

typedef __attribute__((ext_vector_type(8))) short short8;
typedef __attribute__((ext_vector_type(4))) float f32x4;
typedef __attribute__((ext_vector_type(4))) unsigned short us4;
typedef unsigned short u16;
typedef unsigned int u32;

#define SCALE 0.17677669529663687f  // 1/sqrt(32)
#define MSHIFT 20.0f

__device__ __forceinline__ float b2f(u16 u) {
  union { u32 i; float f; } v; v.i = ((u32)u) << 16; return v.f;
}
__device__ __forceinline__ u16 f2b(float f) {
  union { float f; u32 i; } v; v.f = f;
  u32 r = v.i + 0x7FFFu + ((v.i >> 16) & 1u);
  return (u16)(r >> 16);
}

// ---------------- adj -> bit pack ----------------
__global__ __launch_bounds__(256) void k_pack(const int* __restrict__ adj,
                                              u32* __restrict__ packed) {
  unsigned int i = blockIdx.x * 256u + threadIdx.x;
  unsigned long long m = __ballot(adj[i] != 0);
  int lane = threadIdx.x & 63;
  if (lane == 0)       packed[i >> 5] = (u32)m;
  else if (lane == 32) packed[i >> 5] = (u32)(m >> 32);
}

// ---------------- 256x256 transpose f32 -> bf16 (x4 matrices) ----------------
__global__ __launch_bounds__(256) void k_transpose4(
    const float* __restrict__ w0, const float* __restrict__ w1,
    const float* __restrict__ w2, const float* __restrict__ w3,
    u16* __restrict__ o0, u16* __restrict__ o1,
    u16* __restrict__ o2, u16* __restrict__ o3) {
  const float* in; u16* out;
  int z = blockIdx.z;
  if (z == 0) { in = w0; out = o0; }
  else if (z == 1) { in = w1; out = o1; }
  else if (z == 2) { in = w2; out = o2; }
  else { in = w3; out = o3; }
  __shared__ u16 t[32][33];
  int tx = threadIdx.x & 31, ty = threadIdx.x >> 5;  // ty 0..7
  int x0 = blockIdx.x * 32, y0 = blockIdx.y * 32;
  for (int j = 0; j < 32; j += 8)
    t[ty + j][tx] = f2b(in[(y0 + ty + j) * 256 + x0 + tx]);
  __syncthreads();
  for (int j = 0; j < 32; j += 8) out[(x0 + ty + j) * 256 + y0 + tx] = t[tx][ty + j];
}

// ---------------- QKV projection ----------------
// wt = [768][256] bf16 (Wq^T|Wk^T|Wv^T). x f32. Writes q,k bf16 [B,H,N,32],
// v bf16 transposed [B,H,32,N].
__global__ __launch_bounds__(256) void k_qkv(
    const float* __restrict__ x, const u16* __restrict__ wt,
    const float* __restrict__ bq, const float* __restrict__ bk,
    const float* __restrict__ bv,
    u16* __restrict__ qw, u16* __restrict__ kw, u16* __restrict__ vt) {
  int l = threadIdx.x & 63, w = threadIdx.x >> 6;
  int lr = l & 15, lg = l >> 4;
  int row0 = blockIdx.y * 64 + w * 16;
  int c0 = blockIdx.x * 64;
  f32x4 acc[4] = {};
  const float* xr = x + (size_t)(row0 + lr) * 256 + lg * 8;
  const u16* wr = wt + (c0 + lr) * 256 + lg * 8;
  for (int k0 = 0; k0 < 256; k0 += 32) {
    f32x4 f0 = *(const f32x4*)(xr + k0);
    f32x4 f1 = *(const f32x4*)(xr + k0 + 4);
    short8 a;
    a[0] = (short)f2b(f0[0]); a[1] = (short)f2b(f0[1]);
    a[2] = (short)f2b(f0[2]); a[3] = (short)f2b(f0[3]);
    a[4] = (short)f2b(f1[0]); a[5] = (short)f2b(f1[1]);
    a[6] = (short)f2b(f1[2]); a[7] = (short)f2b(f1[3]);
#pragma unroll
    for (int ct = 0; ct < 4; ct++) {
      short8 bb = *(const short8*)(wr + ct * 16 * 256 + k0);
      acc[ct] = __builtin_amdgcn_mfma_f32_16x16x32_bf16(a, bb, acc[ct], 0, 0, 0);
    }
  }
  int mtx = blockIdx.x >> 2;  // 0=q 1=k 2=v
  const float* bias = (mtx == 0) ? bq : ((mtx == 1) ? bk : bv);
  int b = row0 >> 11, nbase = row0 & 2047;
#pragma unroll
  for (int ct = 0; ct < 4; ct++) {
    int cc = (c0 + ct * 16 + lr) & 255;
    int h = cc >> 5, d = cc & 31;
    float bs = bias[cc];
    if (mtx < 2) {
      u16* dst = (mtx == 0) ? qw : kw;
#pragma unroll
      for (int rr = 0; rr < 4; rr++) {
        int n = nbase + lg * 4 + rr;
        dst[((b * 8 + h) * 2048 + n) * 32 + d] = f2b(acc[ct][rr] + bs);
      }
    } else {
      us4 pk;
#pragma unroll
      for (int rr = 0; rr < 4; rr++) pk[rr] = f2b(acc[ct][rr] + bs);
      *(us4*)(vt + (size_t)((b * 8 + h) * 32 + d) * 2048 + nbase + lg * 4) = pk;
    }
  }
}

// ---------------- attention pass 1: row sum of exp(s-20) ----------------
__global__ __launch_bounds__(512) void k_pass1(
    const u16* __restrict__ qw, const u16* __restrict__ kw,
    const u32* __restrict__ packed, float* __restrict__ linv) {
  int l = threadIdx.x & 63, h = threadIdx.x >> 6;
  int lr = l & 15, lg = l >> 4;
  int b = blockIdx.y, q0 = blockIdx.x * 64;
  const u16* qb = qw + (size_t)((b * 8 + h) * 2048) * 32;
  const u16* kb = kw + (size_t)((b * 8 + h) * 2048) * 32;
  short8 aq[4];
#pragma unroll
  for (int qs = 0; qs < 4; qs++)
    aq[qs] = *(const short8*)(qb + (q0 + qs * 16 + lr) * 32 + lg * 8);
  float ls[4][4] = {};
  const u32* pkb = packed + (size_t)(b * 2048 + q0) * 64;
  for (int kt = 0; kt < 128; kt++) {
    short8 bk = *(const short8*)(kb + (kt * 16 + lr) * 32 + lg * 8);
    int key = kt * 16 + lr;
    int word = key >> 5, bit = key & 31;
#pragma unroll
    for (int qs = 0; qs < 4; qs++) {
      f32x4 z = {};
      f32x4 s = __builtin_amdgcn_mfma_f32_16x16x32_bf16(aq[qs], bk, z, 0, 0, 0);
#pragma unroll
      for (int rr = 0; rr < 4; rr++) {
        u32 mword = pkb[(qs * 16 + lg * 4 + rr) * 64 + word];
        float e = __expf(fminf(fmaf(s[rr], SCALE, -MSHIFT), 0.0f));
        ls[qs][rr] += ((mword >> bit) & 1u) ? e : 0.0f;
      }
    }
  }
#pragma unroll
  for (int qs = 0; qs < 4; qs++)
#pragma unroll
    for (int rr = 0; rr < 4; rr++) {
      float v = ls[qs][rr];
      v += __shfl_xor(v, 1); v += __shfl_xor(v, 2);
      v += __shfl_xor(v, 4); v += __shfl_xor(v, 8);
      ls[qs][rr] = v;
    }
  if (lr == 0) {
#pragma unroll
    for (int qs = 0; qs < 4; qs++)
#pragma unroll
      for (int rr = 0; rr < 4; rr++) {
        int n = q0 + qs * 16 + lg * 4 + rr;
        linv[(b * 8 + h) * 2048 + n] =
            fminf(1.0f / fmaxf(ls[qs][rr], 1e-30f), 1e30f);
      }
  }
}

// ---------------- attention pass 2: probs -> mean(f32) + PV ----------------
// Block: (b, 32 q-rows) x 8 heads(waves). Per 64-key chunk: P tiles in plain
// [16][64] LDS, PV MFMA from own tile, mean = sum over waves / 8 -> f32 out2.
__global__ __launch_bounds__(512) void k_pass2(
    const u16* __restrict__ qw, const u16* __restrict__ kw,
    const u16* __restrict__ vt, const u32* __restrict__ packed,
    const float* __restrict__ linv, u16* __restrict__ ao,
    float* __restrict__ out2) {
  __shared__ __align__(16) u16 P[8][2][1024];  // [wave][qsub][16 x 64]
  int l = threadIdx.x & 63, h = threadIdx.x >> 6;
  int lr = l & 15, lg = l >> 4;
  int b = blockIdx.y, q0 = blockIdx.x * 32;
  const u16* qb = qw + (size_t)((b * 8 + h) * 2048) * 32;
  const u16* kb = kw + (size_t)((b * 8 + h) * 2048) * 32;
  const u16* vb = vt + (size_t)((b * 8 + h) * 32) * 2048;
  short8 aq[2];
  float li[2][4];
#pragma unroll
  for (int qs = 0; qs < 2; qs++) {
    aq[qs] = *(const short8*)(qb + (q0 + qs * 16 + lr) * 32 + lg * 8);
#pragma unroll
    for (int rr = 0; rr < 4; rr++)
      li[qs][rr] = linv[(b * 8 + h) * 2048 + q0 + qs * 16 + lg * 4 + rr];
  }
  f32x4 acc[2][2] = {};
  const u32* pkb = packed + (size_t)(b * 2048 + q0) * 64;
  for (int ch = 0; ch < 32; ch++) {
#pragma unroll
    for (int kt = 0; kt < 4; kt++) {
      int ktg = ch * 4 + kt;
      short8 bk = *(const short8*)(kb + (ktg * 16 + lr) * 32 + lg * 8);
      int key = ktg * 16 + lr;
      int word = key >> 5, bit = key & 31;
#pragma unroll
      for (int qs = 0; qs < 2; qs++) {
        f32x4 z = {};
        f32x4 s = __builtin_amdgcn_mfma_f32_16x16x32_bf16(aq[qs], bk, z, 0, 0, 0);
#pragma unroll
        for (int rr = 0; rr < 4; rr++) {
          u32 mword = pkb[(qs * 16 + lg * 4 + rr) * 64 + word];
          float e = __expf(fminf(fmaf(s[rr], SCALE, -MSHIFT), 0.0f));
          float p = ((mword >> bit) & 1u) ? fminf(e * li[qs][rr], 1.0f) : 0.0f;
          P[h][qs][(lg * 4 + rr) * 64 + kt * 16 + lr] = f2b(p);
        }
      }
    }
    // PV from own wave's P tile (same-wave LDS write->read is ordered)
#pragma unroll
    for (int qs = 0; qs < 2; qs++)
#pragma unroll
      for (int k2 = 0; k2 < 2; k2++) {
        short8 pa = *(const short8*)&P[h][qs][lr * 64 + k2 * 32 + lg * 8];
#pragma unroll
        for (int dt = 0; dt < 2; dt++) {
          short8 bv = *(const short8*)(vb + (dt * 16 + lr) * 2048 +
                                       ch * 64 + k2 * 32 + lg * 8);
          acc[qs][dt] =
              __builtin_amdgcn_mfma_f32_16x16x32_bf16(pa, bv, acc[qs][dt], 0, 0, 0);
        }
      }
    __syncthreads();
    {  // attn-mean: sum the 8 waves' P tiles -> f32 out
      int t = threadIdx.x;
      int row32 = t >> 4, col0 = (t & 15) * 4;
      int qsel = row32 >> 4, r16 = row32 & 15;
      int idx = r16 * 64 + col0;
      float s0 = 0.f, s1 = 0.f, s2 = 0.f, s3 = 0.f;
#pragma unroll
      for (int w8 = 0; w8 < 8; w8++) {
        us4 v = *(const us4*)&P[w8][qsel][idx];
        s0 += b2f(v[0]); s1 += b2f(v[1]); s2 += b2f(v[2]); s3 += b2f(v[3]);
      }
      f32x4 o;
      o[0] = s0 * 0.125f; o[1] = s1 * 0.125f;
      o[2] = s2 * 0.125f; o[3] = s3 * 0.125f;
      *(f32x4*)(out2 + (size_t)(b * 2048 + q0 + row32) * 2048 + ch * 64 + col0) = o;
    }
    __syncthreads();
  }
#pragma unroll
  for (int qs = 0; qs < 2; qs++)
#pragma unroll
    for (int dt = 0; dt < 2; dt++)
#pragma unroll
      for (int rr = 0; rr < 4; rr++) {
        int n = q0 + qs * 16 + lg * 4 + rr;
        ao[(size_t)(b * 2048 + n) * 256 + h * 32 + dt * 16 + lr] =
            f2b(acc[qs][dt][rr]);
      }
}

// ---------------- out-proj + LayerNorm -> f32 out ----------------
__global__ __launch_bounds__(256) void k_oproj(
    const u16* __restrict__ ao, const u16* __restrict__ wto,
    const float* __restrict__ bo, const float* __restrict__ gamma,
    const float* __restrict__ beta, float* __restrict__ out) {
  int l = threadIdx.x & 63, w = threadIdx.x >> 6;
  int lr = l & 15, lg = l >> 4;
  int row0 = blockIdx.x * 64 + w * 16;
  f32x4 acc[16] = {};
  const u16* ar = ao + (size_t)(row0 + lr) * 256 + lg * 8;
  const u16* wr = wto + lr * 256 + lg * 8;
  for (int k0 = 0; k0 < 256; k0 += 32) {
    short8 a = *(const short8*)(ar + k0);
#pragma unroll
    for (int ct = 0; ct < 16; ct++) {
      short8 bb = *(const short8*)(wr + ct * 16 * 256 + k0);
      acc[ct] = __builtin_amdgcn_mfma_f32_16x16x32_bf16(a, bb, acc[ct], 0, 0, 0);
    }
  }
  float sum[4] = {0, 0, 0, 0}, sq[4] = {0, 0, 0, 0};
#pragma unroll
  for (int ct = 0; ct < 16; ct++) {
    float bs = bo[ct * 16 + lr];
#pragma unroll
    for (int rr = 0; rr < 4; rr++) {
      float v = acc[ct][rr] + bs;
      acc[ct][rr] = v;
      sum[rr] += v; sq[rr] += v * v;
    }
  }
#pragma unroll
  for (int rr = 0; rr < 4; rr++) {
    float s = sum[rr], q = sq[rr];
    s += __shfl_xor(s, 1); s += __shfl_xor(s, 2);
    s += __shfl_xor(s, 4); s += __shfl_xor(s, 8);
    q += __shfl_xor(q, 1); q += __shfl_xor(q, 2);
    q += __shfl_xor(q, 4); q += __shfl_xor(q, 8);
    float mu = s * (1.0f / 256.0f);
    float var = fmaxf(q * (1.0f / 256.0f) - mu * mu, 0.0f);
    sum[rr] = mu;
    sq[rr] = rsqrtf(var + 1e-5f);
  }
#pragma unroll
  for (int ct = 0; ct < 16; ct++) {
    float g = gamma[ct * 16 + lr], be = beta[ct * 16 + lr];
#pragma unroll
    for (int rr = 0; rr < 4; rr++) {
      int n = row0 + lg * 4 + rr;
      out[(size_t)n * 256 + ct * 16 + lr] =
          ((acc[ct][rr] - sum[rr]) * sq[rr]) * g + be;
    }
  }
}

extern "C" void kernel_launch(void* const* d_in, const int* in_sizes, int n_in,
                              void* d_out, int out_size, void* d_ws, size_t ws_size,
                              hipStream_t stream) {
  const float* x    = (const float*)d_in[0];
  const int*   adj  = (const int*)d_in[1];
  const float* Wq   = (const float*)d_in[2];
  const float* bq   = (const float*)d_in[3];
  const float* Wk   = (const float*)d_in[4];
  const float* bk   = (const float*)d_in[5];
  const float* Wv   = (const float*)d_in[6];
  const float* bv   = (const float*)d_in[7];
  const float* Wo   = (const float*)d_in[8];
  const float* bo   = (const float*)d_in[9];
  const float* gamma= (const float*)d_in[10];
  const float* beta = (const float*)d_in[11];

  char* ws = (char*)d_ws;
  // ws layout (bytes): wtq 0 | wtk 128K | wtv 256K | wto 384K | qw 512K(8M) |
  // kw | vt | ao | packed(4M) | linv(512K)  -- total ~38.8 MB
  u16* wtq = (u16*)(ws + 0);
  u16* wtk = (u16*)(ws + 131072);
  u16* wtv = (u16*)(ws + 262144);
  u16* wto = (u16*)(ws + 393216);
  u16* qw  = (u16*)(ws + 524288);
  u16* kw  = (u16*)(ws + 8912896);
  u16* vt  = (u16*)(ws + 17301504);
  u16* ao  = (u16*)(ws + 25690112);
  u32* pk  = (u32*)(ws + 34078720);
  float* linv = (float*)(ws + 38273024);

  float* out  = (float*)d_out;
  float* out2 = out + (size_t)8 * 2048 * 256;

  k_pack<<<dim3(131072), dim3(256), 0, stream>>>(adj, pk);
  k_transpose4<<<dim3(8, 8, 4), dim3(256), 0, stream>>>(Wq, Wk, Wv, Wo,
                                                        wtq, wtk, wtv, wto);
  k_qkv<<<dim3(12, 256), dim3(256), 0, stream>>>(x, wtq, bq, bk, bv, qw, kw, vt);
  k_pass1<<<dim3(32, 8), dim3(512), 0, stream>>>(qw, kw, pk, linv);
  k_pass2<<<dim3(64, 8), dim3(512), 0, stream>>>(qw, kw, vt, pk, linv, ao, out2);
  k_oproj<<<dim3(256), dim3(256), 0, stream>>>(ao, wto, bo, gamma, beta, out);
}